// Round 13
// baseline (356.637 us; speedup 1.0000x reference)
//
#include <hip/hip_runtime.h>
#include <math.h>

// Problem constants (from reference)
#define NNODES 100000
#define NREL 500
#define E1 288000
#define ETOT 320000
#define LALPHA 0.2f
#define SEPS 1e-16f
#define NB_SCAN ((NNODES + 255) / 256)  // 391 blocks of 256 for the scan
#define GTILES 6250                      // 100000 / 16 row-tiles, exact
#define GTPB 5                           // tiles per block
#define GGRID (GTILES / GTPB)            // 1250 blocks, exact
#define EB 1250                          // 320000 / 256, exact

typedef __attribute__((ext_vector_type(8))) short bf16x8;
typedef __attribute__((ext_vector_type(4))) float f32x4;

// fp32 -> bf16 (round-to-nearest-even), header-independent
__device__ __forceinline__ unsigned short f2bf(float x) {
  unsigned int u = __float_as_uint(x);
  unsigned int r = (u + 0x7fffu + ((u >> 16) & 1u)) >> 16;
  return (unsigned short)r;
}
// pack two fp32 as bf16 pair (lo, hi) in one uint
__device__ __forceinline__ unsigned int packbf2(float lo, float hi) {
  return (unsigned int)f2bf(lo) | ((unsigned int)f2bf(hi) << 16);
}
__device__ __forceinline__ float unpk_lo(unsigned int u) { return __uint_as_float(u << 16); }
__device__ __forceinline__ float unpk_hi(unsigned int u) {
  return __uint_as_float(u & 0xffff0000u);
}
__device__ __forceinline__ float lrelu(float e) { return (e >= 0.f) ? e : LALPHA * e; }
// clamped exp: shift-free softmax weight (logits here are O(1); clamp only for safety)
__device__ __forceinline__ float wexp(float lg) { return __expf(fminf(lg, 60.f)); }

// ---------------- wave (64-lane) reductions ----------------
__device__ __forceinline__ float wave_sum64(float v) {
#pragma unroll
  for (int o = 32; o >= 1; o >>= 1) v += __shfl_xor(v, o, 64);
  return v;
}
__device__ __forceinline__ int wave_sum64i(int v) {
#pragma unroll
  for (int o = 32; o >= 1; o >>= 1) v += __shfl_xor(v, o, 64);
  return v;
}
// reduce across the 16 lanes of a colv-group (bits 0..3)
__device__ __forceinline__ float red16(float v) {
  v += __shfl_xor(v, 1, 64);
  v += __shfl_xor(v, 2, 64);
  v += __shfl_xor(v, 4, 64);
  v += __shfl_xor(v, 8, 64);
  return v;
}

// ---------------- CSR scan ----------------
__global__ void k_zero_int(int* __restrict__ p, int n) {
  int i = blockIdx.x * blockDim.x + threadIdx.x;
  if (i < n) p[i] = 0;
}

__global__ void k_scan_a(const int* __restrict__ cnt, int* __restrict__ rowstart,
                         int* __restrict__ blockTot) {
  __shared__ int s[256];
  int t = threadIdx.x;
  int idx = blockIdx.x * 256 + t;
  int v = (idx < NNODES) ? cnt[idx] : 0;
  s[t] = v;
  __syncthreads();
  for (int off = 1; off < 256; off <<= 1) {
    int xv = (t >= off) ? s[t - off] : 0;
    __syncthreads();
    s[t] += xv;
    __syncthreads();
  }
  if (idx < NNODES) rowstart[idx] = s[t] - v;  // exclusive within block
  if (t == 255) blockTot[blockIdx.x] = s[255];
}

// Fused scan_b+scan_c: each block redundantly reduces blockTot[0..bid) (391 ints, L2-hot).
__global__ void k_scan_c(int* __restrict__ rowstart, const int* __restrict__ blockTot,
                         int* __restrict__ cursor) {
  __shared__ int wred[4];
  int t = threadIdx.x;
  int bid = blockIdx.x;
  int v = 0;
  if (t < bid) v += blockTot[t];
  int t2 = t + 256;
  if (t2 < bid) v += blockTot[t2];  // bid < NB_SCAN=391, safe
  v = wave_sum64i(v);
  if ((t & 63) == 0) wred[t >> 6] = v;
  __syncthreads();
  int off = wred[0] + wred[1] + wred[2] + wred[3];
  int idx = bid * 256 + t;
  if (idx < NNODES) {
    int val = rowstart[idx] + off;
    rowstart[idx] = val;
    cursor[idx] = val;
  }
  if (idx == 0) rowstart[NNODES] = ETOT;
}

// ---------------- fused prep: count | relprep1 | relprep2f | packb ----------------
// blocks [0,1250): edge count; [1250,1500): relprep1 (2 rel/blk);
// [1500,1750): relprep2f (2 rel/blk); [1750,2006): packb (2 c-slots/blk).
#define PREP_GRID (EB + 250 + 250 + 256)
__global__ __launch_bounds__(256) void k_prep(
    const int* __restrict__ srcA, int* __restrict__ cnt, const float* __restrict__ r,
    const float* __restrict__ Wh, const float* __restrict__ ah,
    unsigned int* __restrict__ rW1p, float* __restrict__ srel1,
    const float* __restrict__ Wr, const float* __restrict__ Wo,
    const float* __restrict__ ao, unsigned int* __restrict__ rW2p,
    float* __restrict__ srel2, float* __restrict__ r2out,
    unsigned short* __restrict__ Wb1, unsigned short* __restrict__ Wb2) {
  __shared__ float sm[6 * 128];
  const int b = blockIdx.x;
  const int tid = threadIdx.x;
  if (b < EB) {
    // ---- edge count ----
    int e = b * 256 + tid;
    if (e < ETOT) atomicAdd(&cnt[srcA[e]], 1);
  } else if (b < EB + 250) {
    // ---- relprep1: rW1p + srel1 ----
    float(*vals)[128] = (float(*)[128])sm;
    int rsel = tid >> 7, tid2 = tid & 127;
    int t = (b - EB) * 2 + rsel;
    int h = tid2 >> 6, kk = tid2 & 63;
    const float* wcol = Wh + h * 24576 + 256 * 64 + kk;
    const float* rrow = r + t * 128;
    float acc = 0.f;
#pragma unroll 4
    for (int d = 0; d < 128; ++d) acc = fmaf(rrow[d], wcol[d * 64], acc);
    vals[rsel][tid2] = acc;
    float p = wave_sum64(acc * ah[h * 64 + kk]);
    if (kk == 0) srel1[t * 2 + h] = p;
    __syncthreads();
    if (tid2 < 64) rW1p[t * 64 + tid2] = packbf2(vals[rsel][2 * tid2], vals[rsel][2 * tid2 + 1]);
  } else if (b < EB + 500) {
    // ---- relprep2f: r2 + rW2p + srel2 ----
    float(*v2)[128] = (float(*)[128])sm;
    float(*s)[128] = (float(*)[128])(sm + 2 * 128);
    float(*vals)[128] = (float(*)[128])(sm + 4 * 128);
    int rsel = tid >> 7, k = tid & 127;
    int t = (b - EB - 250) * 2 + rsel;
    float a2 = 0.f;
#pragma unroll 4
    for (int d = 0; d < 128; ++d) a2 = fmaf(r[t * 128 + d], Wr[d * 128 + k], a2);
    r2out[t * 128 + k] = a2;
    v2[rsel][k] = a2;
    __syncthreads();
    float acc = 0.f;
#pragma unroll 4
    for (int d = 0; d < 128; ++d) acc = fmaf(v2[rsel][d], Wo[(256 + d) * 128 + k], acc);
    vals[rsel][k] = acc;
    s[rsel][k] = acc * ao[k];
    __syncthreads();
    for (int off = 64; off >= 1; off >>= 1) {
      if (k < off) s[rsel][k] += s[rsel][k + off];
      __syncthreads();
    }
    if (k == 0) srel2[t] = s[rsel][0];
    if (k < 64) rW2p[t * 64 + k] = packbf2(vals[rsel][2 * k], vals[rsel][2 * k + 1]);
  } else {
    // ---- packb: both layers ----
    int idx = (b - EB - 500) * 2 + (tid >> 7);  // 0..511
    int layer = idx >> 8, c = idx & 255, d = tid & 127;
    if (layer == 0) {
      int h = (c >> 6) & 1, part = c >> 7, kc = c & 63;
      Wb1[c * 128 + d] = f2bf(Wh[h * 24576 + (part * 128 + d) * 64 + kc]);
    } else {
      int part = c >> 7, kc = c & 127;
      Wb2[c * 128 + d] = f2bf(Wo[(part * 128 + d) * 128 + kc]);
    }
  }
}

// ---------------- MFMA GEMM body: xWp[N][128 uints] (plain bf16 row) = X @ Wb^T --------
// Wave owns 64 CONTIGUOUS cols; B resident in 64 VGPR. No LDS/barriers/atomics.
template <int LAYER>
__device__ __forceinline__ void gemm_body(int bid, const void* __restrict__ Xin,
                                          const unsigned short* __restrict__ Wb,
                                          const float* __restrict__ avec,
                                          unsigned int* __restrict__ xWp,
                                          float* __restrict__ sc) {
  const int lane = threadIdx.x & 63;
  const int wave = threadIdx.x >> 6;
  const int colv = lane & 15;
  const int kg = lane >> 4;

  bf16x8 b[4][4];
#pragma unroll
  for (int t = 0; t < 4; ++t)
#pragma unroll
    for (int s = 0; s < 4; ++s)
      b[t][s] = *(const bf16x8*)(Wb + (size_t)(wave * 64 + t * 16 + colv) * 128 + s * 32 +
                                 kg * 8);
  float av[4];
#pragma unroll
  for (int t = 0; t < 4; ++t) av[t] = avec[(wave & 1) * 64 + t * 16 + colv];
  const int slot = (LAYER == 1) ? (((wave & 1) << 1) | (wave >> 1)) : wave;

  const float4* xf4 = (const float4*)Xin;
  const uint4* xu4 = (const uint4*)Xin;
  int tile = bid * GTPB;

  float4 cf[8];
  uint4 cu[4];
  {
    int ar = tile * 16 + colv;
    if (LAYER == 1) {
      int base = ar * 32 + kg * 2;
#pragma unroll
      for (int s = 0; s < 4; ++s) {
        cf[2 * s] = xf4[base + s * 8];
        cf[2 * s + 1] = xf4[base + s * 8 + 1];
      }
    } else {
      int base = ar * 16 + kg;
#pragma unroll
      for (int s = 0; s < 4; ++s) cu[s] = xu4[base + s * 4];
    }
  }

  for (int it = 0; it < GTPB; ++it, ++tile) {
    float4 nf[8];
    uint4 nu[4];
    const bool hasnext = (it + 1 < GTPB);
    if (hasnext) {
      int ar = (tile + 1) * 16 + colv;
      if (LAYER == 1) {
        int base = ar * 32 + kg * 2;
#pragma unroll
        for (int s = 0; s < 4; ++s) {
          nf[2 * s] = xf4[base + s * 8];
          nf[2 * s + 1] = xf4[base + s * 8 + 1];
        }
      } else {
        int base = ar * 16 + kg;
#pragma unroll
        for (int s = 0; s < 4; ++s) nu[s] = xu4[base + s * 4];
      }
    }

    bf16x8 a[4];
    if (LAYER == 1) {
#pragma unroll
      for (int s = 0; s < 4; ++s) {
        union {
          unsigned short us[8];
          bf16x8 v;
        } u;
        u.us[0] = f2bf(cf[2 * s].x); u.us[1] = f2bf(cf[2 * s].y);
        u.us[2] = f2bf(cf[2 * s].z); u.us[3] = f2bf(cf[2 * s].w);
        u.us[4] = f2bf(cf[2 * s + 1].x); u.us[5] = f2bf(cf[2 * s + 1].y);
        u.us[6] = f2bf(cf[2 * s + 1].z); u.us[7] = f2bf(cf[2 * s + 1].w);
        a[s] = u.v;
      }
    } else {
#pragma unroll
      for (int s = 0; s < 4; ++s) {
        union {
          uint4 q;
          bf16x8 v;
        } u;
        u.q = cu[s];
        a[s] = u.v;
      }
    }

    f32x4 acc[4];
#pragma unroll
    for (int t = 0; t < 4; ++t) acc[t] = (f32x4){0.f, 0.f, 0.f, 0.f};
#pragma unroll
    for (int s = 0; s < 4; ++s)
#pragma unroll
      for (int t = 0; t < 4; ++t)
        acc[t] = __builtin_amdgcn_mfma_f32_16x16x32_bf16(a[s], b[t][s], acc[t], 0, 0, 0);

    const int rbase = tile * 16 + kg * 4;
    const int m = colv >> 1;
    const bool evn = (colv & 1) == 0;
#pragma unroll
    for (int i = 0; i < 4; ++i) {
      unsigned int* orow = xWp + (size_t)(rbase + i) * 128 + wave * 32;
#pragma unroll
      for (int t = 0; t < 4; ++t) {
        float lo = acc[t][i];
        float other = __shfl_xor(lo, 1, 64);
        if (evn) orow[t * 8 + m] = packbf2(lo, other);
      }
      float p = 0.f;
#pragma unroll
      for (int t = 0; t < 4; ++t) p = fmaf(acc[t][i], av[t], p);
      p = red16(p);
      if (colv == 0) sc[(size_t)(rbase + i) * 4 + slot] = p;
    }

    if (hasnext) {
      if (LAYER == 1) {
#pragma unroll
        for (int j = 0; j < 8; ++j) cf[j] = nf[j];
      } else {
#pragma unroll
        for (int j = 0; j < 4; ++j) cu[j] = nu[j];
      }
    }
  }
}

// ---------------- fused scatter ∥ gemm1 (INTERLEAVED roles for co-residency) ----------
// even blocks: scatter edge payload (single int4 store); odd blocks: layer-1 GEMM.
__global__ __launch_bounds__(256) void k_sg1(
    const int* __restrict__ srcA, const int* __restrict__ dstA, const int* __restrict__ et,
    const int* __restrict__ et2, int* __restrict__ cursor, int4* __restrict__ epay,
    const float* __restrict__ x, const unsigned short* __restrict__ Wb1,
    const float* __restrict__ ah, unsigned int* __restrict__ xWp,
    float* __restrict__ sc1) {
  const int bid = blockIdx.x;
  if ((bid & 1) == 0) {
    int e = (bid >> 1) * 256 + threadIdx.x;
    if (e < ETOT) {
      int pos = atomicAdd(&cursor[srcA[e]], 1);
      int t1, t2 = -1;
      if (e < E1) {
        t1 = et[e];
      } else {
        int2 tt = ((const int2*)et2)[e - E1];
        t1 = tt.x;
        t2 = tt.y;
      }
      epay[pos] = make_int4(dstA[e], t1, t2, 0);  // one aligned 16-B store
    }
  } else {
    gemm_body<1>(bid >> 1, x, Wb1, ah, xWp, sc1);
  }
}

__global__ __launch_bounds__(256) void k_gemm2(const void* __restrict__ Xin,
                                               const unsigned short* __restrict__ Wb,
                                               const float* __restrict__ avec,
                                               unsigned int* __restrict__ xWp,
                                               float* __restrict__ sc) {
  gemm_body<2>(blockIdx.x, Xin, Wb, avec, xWp, sc);
}

// ---------------- layer-1 aggregation: uint4 gathers, fused w-compute ----------------
// Lane (q,g): group g handles edge p0+g; lane owns dst-half uints 4q..4q+3 (one uint4).
// Head split at q<8 (uints 0..31 = head0). Output uint jo = 4q+g after 4-group reduce.
__global__ __launch_bounds__(256) void k_agg1(
    const int* __restrict__ rowstart, const int4* __restrict__ epay,
    const unsigned int* __restrict__ xWp, const unsigned int* __restrict__ rW1p,
    const float* __restrict__ sc1, const float2* __restrict__ srel1,
    unsigned int* __restrict__ x1b) {
  int n = blockIdx.x * 4 + (threadIdx.x >> 6);
  int lane = threadIdx.x & 63;
  int q = lane & 15, g = lane >> 4;
  int s0 = rowstart[n];
  int deg = rowstart[n + 1] - s0;
  int jo = 4 * q + g;  // output uint index
  float r0 = 0.f, r1 = 0.f;
  if (deg > 0) {
    float4 scn = ((const float4*)sc1)[n];  // {ss_h0, sd_h0, ss_h1, sd_h1}
    const float ss0 = scn.x, ss1 = scn.z;
    float acL[4] = {0.f, 0.f, 0.f, 0.f}, acH[4] = {0.f, 0.f, 0.f, 0.f};
    float dsum0 = 0.f, dsum1 = 0.f;
    const int pend = s0 + deg;
    for (int p0 = s0; p0 < pend; p0 += 4) {
      int p = p0 + g;  // this group's edge
      float w0 = 0.f, w1 = 0.f;
      int dne = 0, t1e = 0, t2e = -1;
      if (p < pend) {
        int4 ep = epay[p];  // 16-lane same-address broadcast load
        dne = ep.x;
        t1e = ep.y;
        t2e = ep.z;
        float2 sr = srel1[t1e];
        float rel0 = sr.x, rel1 = sr.y;
        if (t2e >= 0) {
          float2 sb = srel1[t2e];
          rel0 += sb.x;
          rel1 += sb.y;
        }
        float4 sdv = ((const float4*)sc1)[dne];
        w0 = wexp(lrelu(ss0 + sdv.y + rel0));
        w1 = wexp(lrelu(ss1 + sdv.w + rel1));
        dsum0 += w0;
        dsum1 += w1;
      }
      uint4 xd = *(const uint4*)(xWp + (size_t)dne * 128 + 64 + 4 * q);
      uint4 rv = *(const uint4*)(rW1p + (size_t)t1e * 64 + 4 * q);
      float rL[4] = {unpk_lo(rv.x), unpk_lo(rv.y), unpk_lo(rv.z), unpk_lo(rv.w)};
      float rH[4] = {unpk_hi(rv.x), unpk_hi(rv.y), unpk_hi(rv.z), unpk_hi(rv.w)};
      if (t2e >= 0) {  // group-uniform branch
        uint4 r2v = *(const uint4*)(rW1p + (size_t)t2e * 64 + 4 * q);
        rL[0] += unpk_lo(r2v.x); rH[0] += unpk_hi(r2v.x);
        rL[1] += unpk_lo(r2v.y); rH[1] += unpk_hi(r2v.y);
        rL[2] += unpk_lo(r2v.z); rH[2] += unpk_hi(r2v.z);
        rL[3] += unpk_lo(r2v.w); rH[3] += unpk_hi(r2v.w);
      }
      float wq = (q < 8) ? w0 : w1;  // lane's 4 uints are one head
      acL[0] = fmaf(wq, unpk_lo(xd.x) + rL[0], acL[0]);
      acH[0] = fmaf(wq, unpk_hi(xd.x) + rH[0], acH[0]);
      acL[1] = fmaf(wq, unpk_lo(xd.y) + rL[1], acL[1]);
      acH[1] = fmaf(wq, unpk_hi(xd.y) + rH[1], acH[1]);
      acL[2] = fmaf(wq, unpk_lo(xd.z) + rL[2], acL[2]);
      acH[2] = fmaf(wq, unpk_hi(xd.z) + rH[2], acH[2]);
      acL[3] = fmaf(wq, unpk_lo(xd.w) + rL[3], acL[3]);
      acH[3] = fmaf(wq, unpk_hi(xd.w) + rH[3], acH[3]);
    }
    // reduce across the 4 groups (lanes q, q+16, q+32, q+48)
#pragma unroll
    for (int k = 0; k < 4; ++k) {
      acL[k] += __shfl_xor(acL[k], 16, 64);
      acL[k] += __shfl_xor(acL[k], 32, 64);
      acH[k] += __shfl_xor(acH[k], 16, 64);
      acH[k] += __shfl_xor(acH[k], 32, 64);
    }
    dsum0 += __shfl_xor(dsum0, 16, 64);
    dsum0 += __shfl_xor(dsum0, 32, 64);
    dsum1 += __shfl_xor(dsum1, 16, 64);
    dsum1 += __shfl_xor(dsum1, 32, 64);
    float aL = (g == 0) ? acL[0] : (g == 1) ? acL[1] : (g == 2) ? acL[2] : acL[3];
    float aH = (g == 0) ? acH[0] : (g == 1) ? acH[1] : (g == 2) ? acH[2] : acH[3];
    float dsel = (q < 8) ? dsum0 : dsum1;
    float isel = 1.f / (dsel + SEPS);
    unsigned int us = xWp[(size_t)n * 128 + jo];  // src half
    float o0 = (aL + dsel * unpk_lo(us)) * isel;
    float o1 = (aH + dsel * unpk_hi(us)) * isel;
    r0 = (o0 > 0.f) ? o0 : __expf(o0) - 1.f;  // elu (concat=True)
    r1 = (o1 > 0.f) ? o1 : __expf(o1) - 1.f;
  }
  x1b[(size_t)n * 64 + jo] = packbf2(r0, r1);  // plain bf16 row (cols 2jo, 2jo+1)
}

// ---------------- layer-2 aggregation: same structure, fp32 out ----------------
// sc2[n] = {p0a, p0b, p1a, p1b}: ss = p0a+p0b, sd = p1a+p1b
__global__ __launch_bounds__(256) void k_agg2(
    const int* __restrict__ rowstart, const int4* __restrict__ epay,
    const unsigned int* __restrict__ xWp, const unsigned int* __restrict__ rW2p,
    const float* __restrict__ sc2, const float* __restrict__ srel2,
    float* __restrict__ outp) {
  int n = blockIdx.x * 4 + (threadIdx.x >> 6);
  int lane = threadIdx.x & 63;
  int q = lane & 15, g = lane >> 4;
  int s0 = rowstart[n];
  int deg = rowstart[n + 1] - s0;
  int jo = 4 * q + g;
  float r0 = 0.f, r1 = 0.f;
  if (deg > 0) {
    float4 scn = ((const float4*)sc2)[n];
    const float ss = scn.x + scn.y;  // src-part scalar, wave-uniform
    float acL[4] = {0.f, 0.f, 0.f, 0.f}, acH[4] = {0.f, 0.f, 0.f, 0.f};
    float dsum = 0.f;
    const int pend = s0 + deg;
    for (int p0 = s0; p0 < pend; p0 += 4) {
      int p = p0 + g;
      float w = 0.f;
      int dne = 0, t1e = 0, t2e = -1;
      if (p < pend) {
        int4 ep = epay[p];
        dne = ep.x;
        t1e = ep.y;
        t2e = ep.z;
        float rel = srel2[t1e];
        if (t2e >= 0) rel += srel2[t2e];
        float4 sdv = ((const float4*)sc2)[dne];
        w = wexp(lrelu(ss + (sdv.z + sdv.w) + rel));
        dsum += w;
      }
      uint4 xd = *(const uint4*)(xWp + (size_t)dne * 128 + 64 + 4 * q);
      uint4 rv = *(const uint4*)(rW2p + (size_t)t1e * 64 + 4 * q);
      float rL[4] = {unpk_lo(rv.x), unpk_lo(rv.y), unpk_lo(rv.z), unpk_lo(rv.w)};
      float rH[4] = {unpk_hi(rv.x), unpk_hi(rv.y), unpk_hi(rv.z), unpk_hi(rv.w)};
      if (t2e >= 0) {
        uint4 r2v = *(const uint4*)(rW2p + (size_t)t2e * 64 + 4 * q);
        rL[0] += unpk_lo(r2v.x); rH[0] += unpk_hi(r2v.x);
        rL[1] += unpk_lo(r2v.y); rH[1] += unpk_hi(r2v.y);
        rL[2] += unpk_lo(r2v.z); rH[2] += unpk_hi(r2v.z);
        rL[3] += unpk_lo(r2v.w); rH[3] += unpk_hi(r2v.w);
      }
      acL[0] = fmaf(w, unpk_lo(xd.x) + rL[0], acL[0]);
      acH[0] = fmaf(w, unpk_hi(xd.x) + rH[0], acH[0]);
      acL[1] = fmaf(w, unpk_lo(xd.y) + rL[1], acL[1]);
      acH[1] = fmaf(w, unpk_hi(xd.y) + rH[1], acH[1]);
      acL[2] = fmaf(w, unpk_lo(xd.z) + rL[2], acL[2]);
      acH[2] = fmaf(w, unpk_hi(xd.z) + rH[2], acH[2]);
      acL[3] = fmaf(w, unpk_lo(xd.w) + rL[3], acL[3]);
      acH[3] = fmaf(w, unpk_hi(xd.w) + rH[3], acH[3]);
    }
#pragma unroll
    for (int k = 0; k < 4; ++k) {
      acL[k] += __shfl_xor(acL[k], 16, 64);
      acL[k] += __shfl_xor(acL[k], 32, 64);
      acH[k] += __shfl_xor(acH[k], 16, 64);
      acH[k] += __shfl_xor(acH[k], 32, 64);
    }
    dsum += __shfl_xor(dsum, 16, 64);
    dsum += __shfl_xor(dsum, 32, 64);
    float aL = (g == 0) ? acL[0] : (g == 1) ? acL[1] : (g == 2) ? acL[2] : acL[3];
    float aH = (g == 0) ? acH[0] : (g == 1) ? acH[1] : (g == 2) ? acH[2] : acH[3];
    float inv = 1.f / (dsum + SEPS);
    unsigned int us = xWp[(size_t)n * 128 + jo];
    float o0 = (aL + dsum * unpk_lo(us)) * inv;
    float o1 = (aH + dsum * unpk_hi(us)) * inv;
    r0 = (o0 > 0.f) ? o0 : __expf(o0) - 1.f;  // final elu
    r1 = (o1 > 0.f) ? o1 : __expf(o1) - 1.f;
  }
  ((float2*)outp)[(size_t)n * 64 + jo] = make_float2(r0, r1);  // cols 2jo, 2jo+1
}

// ---------------- launch ----------------
extern "C" void kernel_launch(void* const* d_in, const int* in_sizes, int n_in, void* d_out,
                              int out_size, void* d_ws, size_t ws_size, hipStream_t stream) {
  const int* edge_index = (const int*)d_in[0];
  const int* srcA = edge_index;
  const int* dstA = edge_index + ETOT;
  const float* x = (const float*)d_in[1];
  const float* r = (const float*)d_in[2];
  const int* et = (const int*)d_in[3];
  const int* et2 = (const int*)d_in[4];
  const float* Wh = (const float*)d_in[5];
  const float* ah = (const float*)d_in[6];
  const float* Wo = (const float*)d_in[7];
  const float* ao = (const float*)d_in[8];
  const float* Wr = (const float*)d_in[9];
  float* out = (float*)d_out;
  float* r2out = out + (size_t)NNODES * 128;

  // workspace layout (256-B aligned chunks)
  char* ws = (char*)d_ws;
  size_t o = 0;
  auto alloc = [&](size_t bytes) {
    char* p = ws + o;
    o += (bytes + 255) & ~(size_t)255;
    return p;
  };
  unsigned int* xWp = (unsigned int*)alloc((size_t)NNODES * 128 * 4);  // plain bf16 rows
  float* sc1 = (float*)alloc((size_t)NNODES * 4 * 4);
  float* sc2 = (float*)alloc((size_t)NNODES * 4 * 4);  // 4 slots, summed in agg2
  unsigned int* rW1p = (unsigned int*)alloc((size_t)NREL * 64 * 4);
  float* srel1 = (float*)alloc(2 * NREL * 4);
  unsigned int* rW2p = (unsigned int*)alloc((size_t)NREL * 64 * 4);
  float* srel2 = (float*)alloc(NREL * 4);
  unsigned int* x1b = (unsigned int*)alloc((size_t)NNODES * 64 * 4);  // plain bf16 x1
  unsigned short* Wb1 = (unsigned short*)alloc(256 * 128 * 2);
  unsigned short* Wb2 = (unsigned short*)alloc(256 * 128 * 2);
  int* cnt = (int*)alloc(NNODES * 4);
  int* rowstart = (int*)alloc((NNODES + 1) * 4);
  int* cursor = (int*)alloc(NNODES * 4);
  int* blockTot = (int*)alloc(512 * 4);
  int4* epay = (int4*)alloc((size_t)ETOT * 16);

  // 1. zero cnt
  k_zero_int<<<(NNODES + 255) / 256, 256, 0, stream>>>(cnt, NNODES);
  // 2. fused prep: count | relprep1 | relprep2f | packb
  k_prep<<<PREP_GRID, 256, 0, stream>>>(srcA, cnt, r, Wh, ah, rW1p, srel1, Wr, Wo, ao, rW2p,
                                        srel2, r2out, Wb1, Wb2);
  // 3-4. CSR scan (scan_b fused into scan_c)
  k_scan_a<<<NB_SCAN, 256, 0, stream>>>(cnt, rowstart, blockTot);
  k_scan_c<<<NB_SCAN, 256, 0, stream>>>(rowstart, blockTot, cursor);
  // 5. fused scatter ∥ gemm1 (interleaved)
  k_sg1<<<2 * EB, 256, 0, stream>>>(srcA, dstA, et, et2, cursor, epay, x, Wb1, ah, xWp, sc1);
  // 6. layer-1 aggregation
  k_agg1<<<NNODES / 4, 256, 0, stream>>>(rowstart, epay, xWp, rW1p, sc1,
                                         (const float2*)srel1, x1b);
  // 7. layer-2 GEMM
  k_gemm2<<<GGRID, 256, 0, stream>>>(x1b, Wb2, ao, xWp, sc2);
  // 8. layer-2 aggregation
  k_agg2<<<NNODES / 4, 256, 0, stream>>>(rowstart, epay, xWp, rW2p, sc2, srel2, out);
}